// Round 1
// baseline (1345.233 us; speedup 1.0000x reference)
//
#include <hip/hip_runtime.h>
#include <hip/hip_bf16.h>

// Problem: B=4096, L=100 (SEQLEN=99), d=256, K=2d=512.
// x[b,t,:] = [qa[b,t,:], q[b,t,:]]  (t=0..98)
// gate=sigmoid(x@Wg^T+bg), kq=tanh(x@Wk^T+bk), reset=sigmoid(x@Wr^T+br)
// h_0 = exp; h_{t+1} = r_t*h_t + (1-r_t)*(gate_t*kq_t); out[b] = [exp, h_1..h_99]

typedef __attribute__((ext_vector_type(4))) float f32x4;
typedef __attribute__((ext_vector_type(8))) short short8;

union BF8 { short8 s; unsigned short u[8]; };

static constexpr int LDS_STRIDE = 257;           // u32 elems per t-row (256 + 1 pad)
static constexpr int LDS_WORDS  = 99 * LDS_STRIDE;

__device__ __forceinline__ unsigned short f2bf(float f) {
  unsigned int u = __float_as_uint(f);
  return (unsigned short)((u + 0x7fffu + ((u >> 16) & 1u)) >> 16);   // RNE
}

__device__ __forceinline__ float sigm(float x) { return 1.f / (1.f + __expf(-x)); }
__device__ __forceinline__ float tanh_(float x) {
  x = fminf(fmaxf(x, -15.f), 15.f);
  float e = __expf(2.f * x);
  return (e - 1.f) / (e + 1.f);
}

// Pack Wg|Wk|Wr (each 256x512 f32, row-major, row=output col n, col=k) into bf16
// B-fragment order: [nt(48)][ks(16)][lane(64)][j(8)]
// value = W_sel[(nt*16 + (l&15)) & 255][ks*32 + (l>>4)*8 + j],  sel = nt>>4
__global__ void pack_w(const float* __restrict__ Wg, const float* __restrict__ Wk,
                       const float* __restrict__ Wr, unsigned short* __restrict__ out) {
  int idx = blockIdx.x * 256 + threadIdx.x;      // 0 .. 49151  (48*16*64)
  int l = idx & 63;
  int rest = idx >> 6;
  int ks = rest & 15;
  int nt = rest >> 4;                            // 0..47
  int sel = nt >> 4;
  const float* W = (sel == 0) ? Wg : ((sel == 1) ? Wk : Wr);
  int n = ((nt & 15) * 16) + (l & 15);           // 0..255
  const float* p = W + (size_t)n * 512 + ks * 32 + ((l >> 4) * 8);
  unsigned short* o = out + (size_t)idx * 8;
#pragma unroll
  for (int j = 0; j < 8; ++j) o[j] = f2bf(p[j]);
}

template <bool PACKED>
__device__ __forceinline__ short8 ldB(const unsigned short* __restrict__ wpk,
                                      const float* __restrict__ W,
                                      int nt_global, int ks, int l) {
  if constexpr (PACKED) {
    return *(const short8*)(wpk + (((size_t)nt_global * 16 + ks) * 64 + l) * 8);
  } else {
    int n = ((nt_global & 15) * 16) + (l & 15);
    const float* p = W + (size_t)n * 512 + ks * 32 + ((l >> 4) * 8);
    f32x4 v0 = *(const f32x4*)p;
    f32x4 v1 = *(const f32x4*)(p + 4);
    BF8 r;
#pragma unroll
    for (int j = 0; j < 4; ++j) { r.u[j] = f2bf(v0[j]); r.u[4 + j] = f2bf(v1[j]); }
    return r.s;
  }
}

template <bool PACKED>
__global__ __launch_bounds__(512, 2) void fused_kernel(
    const float* __restrict__ q, const float* __restrict__ qa,
    const float* __restrict__ expw,
    const float* __restrict__ Wg, const float* __restrict__ bg,
    const float* __restrict__ Wk, const float* __restrict__ bk,
    const float* __restrict__ Wr, const float* __restrict__ br,
    const unsigned short* __restrict__ wpk,
    float* __restrict__ out) {
  extern __shared__ unsigned int lds[];
  const int b = blockIdx.x;
  const int tid = threadIdx.x;
  const int w = tid >> 6;        // wave 0..7, owns d-cols [w*32, w*32+32)
  const int l = tid & 63;
  const int lrow = l & 15;
  const int lgrp = l >> 4;

  f32x4 accG[7][2], accK[7][2], accR[7][2];
#pragma unroll
  for (int mt = 0; mt < 7; ++mt)
#pragma unroll
    for (int j = 0; j < 2; ++j) {
      accG[mt][j] = (f32x4){0.f, 0.f, 0.f, 0.f};
      accK[mt][j] = (f32x4){0.f, 0.f, 0.f, 0.f};
      accR[mt][j] = (f32x4){0.f, 0.f, 0.f, 0.f};
    }

  const float* xqa = qa + (size_t)b * 100 * 256;   // x[:, 0:256)
  const float* xq  = q  + (size_t)b * 100 * 256;   // x[:, 256:512)

  for (int ks = 0; ks < 16; ++ks) {
    const int k0 = ks * 32 + lgrp * 8;             // this lane's 8-elem k chunk
    const float* xb = (k0 < 256) ? (xqa + k0) : (xq + (k0 - 256));
    BF8 aF[7];
#pragma unroll
    for (int mt = 0; mt < 7; ++mt) {
      int t = mt * 16 + lrow;
      t = (t > 98) ? 98 : t;                       // clamp padded rows (results unused)
      const float* p = xb + t * 256;
      f32x4 v0 = *(const f32x4*)p;
      f32x4 v1 = *(const f32x4*)(p + 4);
#pragma unroll
      for (int j = 0; j < 4; ++j) { aF[mt].u[j] = f2bf(v0[j]); aF[mt].u[4 + j] = f2bf(v1[j]); }
    }
#pragma unroll
    for (int j = 0; j < 2; ++j) {
      short8 bG = ldB<PACKED>(wpk, Wg, w * 2 + j, ks, l);
#pragma unroll
      for (int mt = 0; mt < 7; ++mt)
        accG[mt][j] = __builtin_amdgcn_mfma_f32_16x16x32_bf16(aF[mt].s, bG, accG[mt][j], 0, 0, 0);
      short8 bK = ldB<PACKED>(wpk, Wk, 16 + w * 2 + j, ks, l);
#pragma unroll
      for (int mt = 0; mt < 7; ++mt)
        accK[mt][j] = __builtin_amdgcn_mfma_f32_16x16x32_bf16(aF[mt].s, bK, accK[mt][j], 0, 0, 0);
      short8 bR = ldB<PACKED>(wpk, Wr, 32 + w * 2 + j, ks, l);
#pragma unroll
      for (int mt = 0; mt < 7; ++mt)
        accR[mt][j] = __builtin_amdgcn_mfma_f32_16x16x32_bf16(aF[mt].s, bR, accR[mt][j], 0, 0, 0);
    }
  }

  // biases for this thread's two d columns
  float bgv[2], bkv[2], brv[2];
#pragma unroll
  for (int j = 0; j < 2; ++j) {
    int d = w * 32 + j * 16 + lrow;
    bgv[j] = bg[d]; bkv[j] = bk[d]; brv[j] = br[d];
  }

  // activations in-register; pack (reset, gain) as 2xbf16 into LDS
#pragma unroll
  for (int mt = 0; mt < 7; ++mt)
#pragma unroll
    for (int j = 0; j < 2; ++j)
#pragma unroll
      for (int r = 0; r < 4; ++r) {
        int t = mt * 16 + lgrp * 4 + r;            // D layout: row=(l>>4)*4+reg, col=l&15
        if (t < 99) {
          float g  = sigm(accG[mt][j][r] + bgv[j]);
          float kv = tanh_(accK[mt][j][r] + bkv[j]);
          float rr = sigm(accR[mt][j][r] + brv[j]);
          unsigned int pk = ((unsigned int)f2bf(g * kv) << 16) | (unsigned int)f2bf(rr);
          lds[t * LDS_STRIDE + (w * 32 + j * 16 + lrow)] = pk;
        }
      }

  __syncthreads();

  // 99-step recurrence, one thread per d column
  if (tid < 256) {
    const int d = tid;
    float h = expw[d];
    float* ob = out + (size_t)b * 25600 + d;
    ob[0] = h;                                     // out[b,0,:] = exp
#pragma unroll
    for (int t = 0; t < 99; ++t) {
      unsigned int u = lds[t * LDS_STRIDE + d];
      float rr = __uint_as_float(u << 16);
      float gn = __uint_as_float(u & 0xffff0000u);
      h = __builtin_fmaf(rr, h, (1.f - rr) * gn);
      ob[(t + 1) * 256] = h;
    }
  }
}

extern "C" void kernel_launch(void* const* d_in, const int* in_sizes, int n_in,
                              void* d_out, int out_size, void* d_ws, size_t ws_size,
                              hipStream_t stream) {
  const float* q    = (const float*)d_in[0];
  const float* qa   = (const float*)d_in[1];
  const float* expw = (const float*)d_in[2];
  const float* Wg   = (const float*)d_in[3];
  const float* bg   = (const float*)d_in[4];
  const float* Wk   = (const float*)d_in[5];
  const float* bk   = (const float*)d_in[6];
  const float* Wr   = (const float*)d_in[7];
  const float* br   = (const float*)d_in[8];
  float* out = (float*)d_out;

  const size_t ldsb = (size_t)LDS_WORDS * 4;       // 101,772 B
  const bool packed = ws_size >= (size_t)(48 * 16 * 64 * 8 * 2);

  if (packed) {
    unsigned short* wpk = (unsigned short*)d_ws;
    pack_w<<<192, 256, 0, stream>>>(Wg, Wk, Wr, wpk);
    hipFuncSetAttribute((const void*)&fused_kernel<true>,
                        hipFuncAttributeMaxDynamicSharedMemorySize, (int)ldsb);
    fused_kernel<true><<<4096, 512, ldsb, stream>>>(q, qa, expw, Wg, bg, Wk, bk, Wr, br, wpk, out);
  } else {
    hipFuncSetAttribute((const void*)&fused_kernel<false>,
                        hipFuncAttributeMaxDynamicSharedMemorySize, (int)ldsb);
    fused_kernel<false><<<4096, 512, ldsb, stream>>>(q, qa, expw, Wg, bg, Wk, bk, Wr, br, nullptr, out);
  }
}

// Round 2
// 691.314 us; speedup vs baseline: 1.9459x; 1.9459x over previous
//
#include <hip/hip_runtime.h>
#include <hip/hip_bf16.h>

// Problem: B=4096, L=100 (SEQLEN=99), d=256, K=2d=512.
// x[b,t,:] = [qa[b,t,:], q[b,t,:]]  (t=0..98)
// gate=sigmoid(x@Wg^T+bg), kq=tanh(x@Wk^T+bk), reset=sigmoid(x@Wr^T+br)
// h_0 = exp; h_{t+1} = r_t*h_t + (1-r_t)*(gate_t*kq_t); out[b] = [exp, h_1..h_99]
//
// Round-1 structure: 1 block / b, 512 threads (8 waves), wave w owns d-cols
// [w*32, w*32+32). NEW: x is staged once into LDS as bf16 (XOR-swizzled),
// so A-fragments come from conflict-free ds_read_b128 instead of 8x-redundant
// uncoalesced global loads + 8x-redundant f32->bf16 conversion.

typedef __attribute__((ext_vector_type(4))) float f32x4;
typedef __attribute__((ext_vector_type(8))) short short8;

union BF8 { short8 s; unsigned short u[8]; };

static constexpr int HALF_BYTES = 99 * 512;        // one k-half (256 bf16/row), 50688 B
static constexpr int LDS_BYTES  = 2 * HALF_BYTES;  // 101376 B; rg buffer (99*256*4) aliases this

__device__ __forceinline__ unsigned short f2bf(float f) {
  unsigned int u = __float_as_uint(f);
  return (unsigned short)((u + 0x7fffu + ((u >> 16) & 1u)) >> 16);   // RNE
}

__device__ __forceinline__ float sigm(float x) { return 1.f / (1.f + __expf(-x)); }
__device__ __forceinline__ float tanh_(float x) {
  x = fminf(fmaxf(x, -15.f), 15.f);
  float e = __expf(2.f * x);
  return (e - 1.f) / (e + 1.f);
}

// Pack Wg|Wk|Wr (each 256x512 f32, row-major) into bf16 B-fragment order:
// [nt(48)][ks(16)][lane(64)][j(8)]; value = W_sel[nt%16*16 + (l&15)][ks*32+(l>>4)*8+j]
__global__ void pack_w(const float* __restrict__ Wg, const float* __restrict__ Wk,
                       const float* __restrict__ Wr, unsigned short* __restrict__ out) {
  int idx = blockIdx.x * 256 + threadIdx.x;      // 0 .. 49151  (48*16*64)
  int l = idx & 63;
  int rest = idx >> 6;
  int ks = rest & 15;
  int nt = rest >> 4;                            // 0..47
  int sel = nt >> 4;
  const float* W = (sel == 0) ? Wg : ((sel == 1) ? Wk : Wr);
  int n = ((nt & 15) * 16) + (l & 15);           // 0..255
  const float* p = W + (size_t)n * 512 + ks * 32 + ((l >> 4) * 8);
  unsigned short* o = out + (size_t)idx * 8;
#pragma unroll
  for (int j = 0; j < 8; ++j) o[j] = f2bf(p[j]);
}

template <bool PACKED>
__device__ __forceinline__ short8 ldB(const unsigned short* __restrict__ wpk,
                                      const float* __restrict__ W,
                                      int nt_global, int ks, int l) {
  if constexpr (PACKED) {
    return *(const short8*)(wpk + (((size_t)nt_global * 16 + ks) * 64 + l) * 8);
  } else {
    int n = ((nt_global & 15) * 16) + (l & 15);
    const float* p = W + (size_t)n * 512 + ks * 32 + ((l >> 4) * 8);
    f32x4 v0 = *(const f32x4*)p;
    f32x4 v1 = *(const f32x4*)(p + 4);
    BF8 r;
#pragma unroll
    for (int j = 0; j < 4; ++j) { r.u[j] = f2bf(v0[j]); r.u[4 + j] = f2bf(v1[j]); }
    return r.s;
  }
}

template <bool PACKED>
__global__ __launch_bounds__(512, 2) void fused_kernel(
    const float* __restrict__ q, const float* __restrict__ qa,
    const float* __restrict__ expw,
    const float* __restrict__ Wg, const float* __restrict__ bg,
    const float* __restrict__ Wk, const float* __restrict__ bk,
    const float* __restrict__ Wr, const float* __restrict__ br,
    const unsigned short* __restrict__ wpk,
    float* __restrict__ out) {
  extern __shared__ char smem[];
  unsigned int* rg = (unsigned int*)smem;          // aliases the staged-x region (after barrier)
  const int b = blockIdx.x;
  const int tid = threadIdx.x;
  const int w = tid >> 6;        // wave 0..7, owns d-cols [w*32, w*32+32)
  const int l = tid & 63;
  const int lrow = l & 15;
  const int lgrp = l >> 4;

  const float* xqa = qa + (size_t)b * 100 * 256;   // x[:, 0:256)
  const float* xq  = q  + (size_t)b * 100 * 256;   // x[:, 256:512)

  // ---- stage x -> bf16 LDS (both k-halves), coalesced f32x4 loads,
  //      XOR swizzle: byte-in-row ^= (row&7)<<4  (keeps 8B alignment)
#pragma unroll
  for (int h = 0; h < 2; ++h) {
    const float* src = h ? xq : xqa;
    char* dst = smem + h * HALF_BYTES;
#pragma unroll
    for (int it = 0; it < 13; ++it) {
      int cid = it * 512 + tid;                    // 16B chunk id, 6336 per half
      if (cid < 6336) {
        int row = cid >> 6;                        // t = 0..98  (64 f32x4 per row)
        int c4  = cid & 63;
        f32x4 v = *(const f32x4*)(src + row * 256 + c4 * 4);
        unsigned int w0 = ((unsigned int)f2bf(v[1]) << 16) | f2bf(v[0]);
        unsigned int w1 = ((unsigned int)f2bf(v[3]) << 16) | f2bf(v[2]);
        int byte = row * 512 + ((c4 * 8) ^ ((row & 7) << 4));
        *(unsigned long long*)(dst + byte) = ((unsigned long long)w1 << 32) | w0;
      }
    }
  }
  __syncthreads();

  f32x4 accG[7][2], accK[7][2], accR[7][2];
#pragma unroll
  for (int mt = 0; mt < 7; ++mt)
#pragma unroll
    for (int j = 0; j < 2; ++j) {
      accG[mt][j] = (f32x4){0.f, 0.f, 0.f, 0.f};
      accK[mt][j] = (f32x4){0.f, 0.f, 0.f, 0.f};
      accR[mt][j] = (f32x4){0.f, 0.f, 0.f, 0.f};
    }

  // per-mt row (clamped) and its swizzle constant
  int rowOff[7];                                   // row*512
  int swz[7];                                      // (row&7)<<4
#pragma unroll
  for (int mt = 0; mt < 7; ++mt) {
    int t = mt * 16 + lrow;
    t = (t > 98) ? 98 : t;
    rowOff[mt] = t * 512;
    swz[mt] = (t & 7) << 4;
  }
  const int lgoff = lgrp * 16;                     // byte offset of this lane's 8-bf16 chunk

  for (int ks = 0; ks < 16; ++ks) {
    const char* base = smem + (ks >> 3) * HALF_BYTES;
    const int koff = (ks & 7) * 64 + lgoff;
    BF8 aF[7];
#pragma unroll
    for (int mt = 0; mt < 7; ++mt)
      aF[mt].s = *(const short8*)(base + rowOff[mt] + (koff ^ swz[mt]));   // ds_read_b128
#pragma unroll
    for (int j = 0; j < 2; ++j) {
      short8 bG = ldB<PACKED>(wpk, Wg, w * 2 + j, ks, l);
#pragma unroll
      for (int mt = 0; mt < 7; ++mt)
        accG[mt][j] = __builtin_amdgcn_mfma_f32_16x16x32_bf16(aF[mt].s, bG, accG[mt][j], 0, 0, 0);
      short8 bK = ldB<PACKED>(wpk, Wk, 16 + w * 2 + j, ks, l);
#pragma unroll
      for (int mt = 0; mt < 7; ++mt)
        accK[mt][j] = __builtin_amdgcn_mfma_f32_16x16x32_bf16(aF[mt].s, bK, accK[mt][j], 0, 0, 0);
      short8 bR = ldB<PACKED>(wpk, Wr, 32 + w * 2 + j, ks, l);
#pragma unroll
      for (int mt = 0; mt < 7; ++mt)
        accR[mt][j] = __builtin_amdgcn_mfma_f32_16x16x32_bf16(aF[mt].s, bR, accR[mt][j], 0, 0, 0);
    }
  }
  __syncthreads();                                 // staged x dead; region becomes rg buffer

  // biases for this thread's two d columns
  float bgv[2], bkv[2], brv[2];
#pragma unroll
  for (int j = 0; j < 2; ++j) {
    int d = w * 32 + j * 16 + lrow;
    bgv[j] = bg[d]; bkv[j] = bk[d]; brv[j] = br[d];
  }

  // activations in-register; pack (reset, gain) as 2xbf16 into rg[t][d]
#pragma unroll
  for (int mt = 0; mt < 7; ++mt)
#pragma unroll
    for (int j = 0; j < 2; ++j)
#pragma unroll
      for (int r = 0; r < 4; ++r) {
        int t = mt * 16 + lgrp * 4 + r;            // D layout: row=(l>>4)*4+reg, col=l&15
        if (t < 99) {
          float g  = sigm(accG[mt][j][r] + bgv[j]);
          float kv = tanh_(accK[mt][j][r] + bkv[j]);
          float rr = sigm(accR[mt][j][r] + brv[j]);
          unsigned int pk = ((unsigned int)f2bf(g * kv) << 16) | (unsigned int)f2bf(rr);
          rg[t * 256 + (w * 32 + j * 16 + lrow)] = pk;
        }
      }

  __syncthreads();

  // 99-step recurrence, one thread per d column
  if (tid < 256) {
    const int d = tid;
    float h = expw[d];
    float* ob = out + (size_t)b * 25600 + d;
    ob[0] = h;                                     // out[b,0,:] = exp
#pragma unroll 4
    for (int t = 0; t < 99; ++t) {
      unsigned int u = rg[t * 256 + d];
      float rr = __uint_as_float(u << 16);
      float gn = __uint_as_float(u & 0xffff0000u);
      h = __builtin_fmaf(rr, h, (1.f - rr) * gn);
      ob[(t + 1) * 256] = h;
    }
  }
}

extern "C" void kernel_launch(void* const* d_in, const int* in_sizes, int n_in,
                              void* d_out, int out_size, void* d_ws, size_t ws_size,
                              hipStream_t stream) {
  const float* q    = (const float*)d_in[0];
  const float* qa   = (const float*)d_in[1];
  const float* expw = (const float*)d_in[2];
  const float* Wg   = (const float*)d_in[3];
  const float* bg   = (const float*)d_in[4];
  const float* Wk   = (const float*)d_in[5];
  const float* bk   = (const float*)d_in[6];
  const float* Wr   = (const float*)d_in[7];
  const float* br   = (const float*)d_in[8];
  float* out = (float*)d_out;

  const size_t ldsb = (size_t)LDS_BYTES;           // 101,376 B
  const bool packed = ws_size >= (size_t)(48 * 16 * 64 * 8 * 2);

  if (packed) {
    unsigned short* wpk = (unsigned short*)d_ws;
    pack_w<<<192, 256, 0, stream>>>(Wg, Wk, Wr, wpk);
    hipFuncSetAttribute((const void*)&fused_kernel<true>,
                        hipFuncAttributeMaxDynamicSharedMemorySize, (int)ldsb);
    fused_kernel<true><<<4096, 512, ldsb, stream>>>(q, qa, expw, Wg, bg, Wk, bk, Wr, br, wpk, out);
  } else {
    hipFuncSetAttribute((const void*)&fused_kernel<false>,
                        hipFuncAttributeMaxDynamicSharedMemorySize, (int)ldsb);
    fused_kernel<false><<<4096, 512, ldsb, stream>>>(q, qa, expw, Wg, bg, Wk, bk, Wr, br, nullptr, out);
  }
}